// Round 7
// baseline (83.592 us; speedup 1.0000x reference)
//
#include <hip/hip_runtime.h>
#include <hip/hip_bf16.h>
#include <stdint.h>
#include <stddef.h>

// Problem constants
#define B_    2
#define NREF  3
#define FDIM  256
#define HW    4096
#define DCLS  10
#define RTOT  12288          // NREF*HW reference pixels per batch
#define TT    128            // target pixels per block (4 waves)
#define RR    64             // reference pixels per chunk
#define RS    8              // r-axis split across blocks
#define RPB   1536           // RTOT/RS
#define NCH   24             // RPB/RR
#define NPIX  8192           // B_*HW
#define LOG2E 1.44269504f
#define C0f   (-144.269504f)  // -100*LOG2E; acc init so acc = sim*log2e - 100*log2e

typedef __attribute__((ext_vector_type(8))) short bf16x8;
typedef __attribute__((ext_vector_type(4))) float f32x4;
typedef __attribute__((ext_vector_type(16))) float f32x16;
typedef __attribute__((ext_vector_type(4))) unsigned int u32x4;

__device__ __forceinline__ unsigned short f2bf(float x) {
  union { float f; unsigned u; } v; v.f = x;
  unsigned r = v.u + 0x7fffu + ((v.u >> 16) & 1u);   // RNE
  return (unsigned short)(r >> 16);
}
__device__ __forceinline__ unsigned pk2(float a, float b) {
  return (unsigned)f2bf(a) | ((unsigned)f2bf(b) << 16);
}
// single-instruction packed f32->bf16 (RNE), gfx950
__device__ __forceinline__ unsigned cvtpk(float a, float b) {
  unsigned r;
  asm("v_cvt_pk_bf16_f32 %0, %1, %2" : "=v"(r) : "v"(a), "v"(b));
  return r;
}
// async global->LDS, 16B per lane; LDS dest is wave-uniform base + lane*16
__device__ __forceinline__ void async16(const void* g, void* l) {
  __builtin_amdgcn_global_load_lds(
      (const __attribute__((address_space(1))) void*)g,
      (__attribute__((address_space(3))) void*)l, 16, 0, 0);
}
// one-hot pair: low/high 16-bit bf16 1.0 where label byte matches d
__device__ __forceinline__ unsigned oh2(unsigned word, int d) {
  return ((word & 255u) == (unsigned)d ? 0x3F80u : 0u) |
         (((word >> 8) & 255u) == (unsigned)d ? 0x3F800000u : 0u);
}

// ---------------- kernel 1: fused prep (transpose+convert) + label extract ----------------
// blocks [0,256): ref/tgt -> bf16 rows of 512B with XOR swizzle baked per row.
// ref rows are pre-scaled by LOG2E (sim comes out in log2 units; C0 added via acc init).
__global__ __launch_bounds__(256) void k_pre(const float* __restrict__ ref,
                                             const float* __restrict__ tgt,
                                             const float* __restrict__ rl,
                                             char* __restrict__ outb,
                                             unsigned char* __restrict__ lab8) {
  const int tid = threadIdx.x;
  if (blockIdx.x < 256) {
    const int row = blockIdx.x * 128 + (tid & 127);   // row 0..32767
    const int half = tid >> 7;
    const float* src;
    float scl;
    if (row < B_ * RTOT) {
      const int b = row / RTOT, rr2 = row % RTOT;
      src = ref + ((size_t)(b * NREF + (rr2 >> 12)) * FDIM) * HW + (rr2 & 4095);
      scl = LOG2E;
    } else {
      const int r2 = row - B_ * RTOT;
      src = tgt + ((size_t)(r2 >> 12) * FDIM) * HW + (r2 & 4095);
      scl = 1.0f;
    }
    char* dst = outb + (size_t)row * 512;
    const int sw = (row & 7) << 4;
    for (int ci = 0; ci < 16; ++ci) {
      const int c16 = half * 16 + ci;
      float v[8];
#pragma unroll
      for (int j = 0; j < 8; ++j) v[j] = src[(size_t)(c16 * 8 + j) * HW] * scl;
      u32x4 u;
      u[0] = pk2(v[0], v[1]); u[1] = pk2(v[2], v[3]);
      u[2] = pk2(v[4], v[5]); u[3] = pk2(v[6], v[7]);
      *(u32x4*)(dst + ((c16 * 16) ^ sw)) = u;
    }
  } else {
    const int idx = (blockIdx.x - 256) * 256 + tid;   // < 24576
    if (idx >= B_ * RTOT) return;
    const int b = idx / RTOT, r = idx % RTOT;
    const float* p = rl + ((size_t)((b * NREF + (r >> 12)) * DCLS)) * HW + (r & 4095);
    int v = 0;
#pragma unroll
    for (int d = 1; d < DCLS; ++d)
      if (p[(size_t)d * HW] > 0.5f) v = d;
    lab8[idx] = (unsigned char)v;
  }
}

// ---------------- kernel 2: fused QK-softmax-PV (32x32x16 MFMA) ----------------
// grid = RS(8) * 32(tblocks) * B_(2) = 512 blocks of 256 threads, 2 blocks/CU.
// Wave tile: 32r x 64t (2 col-tiles of 32t). QK: 32 MFMA 32x32x16 per chunk,
// A from LDS, B in regs. PV: acc reg layout IS the PV B-frag layout under the
// sigma r-map r(k) = (k&3)+8*((k&7)>>2)+4*(k>>3), applied to one-hot labels too.
__global__ __launch_bounds__(256, 2) void k_main(const char* __restrict__ refb,
                                                 const char* __restrict__ tgtb,
                                                 const unsigned char* __restrict__ lab8,
                                                 float* __restrict__ pred) {
  __shared__ __align__(16) char Ash[2][RR * 512];   // double-buffered ref chunk, 64 KB

  const int tid = threadIdx.x;
  const int lane = tid & 63;
  const int w = tid >> 6;                // wave 0..3
  const int l31 = lane & 31;
  const int h = lane >> 5;               // k-group
  const int rh = w >> 1, th = w & 1;     // wave sub-tile: 32r x 64t
  const int swz = (lane & 7) << 4;

  const int bid = blockIdx.x;
  const int rs = bid & 7;
  const int tb = (bid >> 3) & 31;
  const int b  = bid >> 8;

  // ---- B fragments in registers: [2 t-tiles][16 ksteps] (128 VGPR) ----
  // bfr[nt][kst] lane: B[t = th*64+nt*32+l31][k = kst*16 + h*8 .. +8]
  bf16x8 bfr[2][16];
  {
    const char* base = tgtb + ((size_t)(b * HW + tb * TT + th * 64)) * 512;
#pragma unroll
    for (int nt = 0; nt < 2; ++nt) {
      const char* rp = base + (size_t)((nt * 32 + l31) * 512);
#pragma unroll
      for (int kst = 0; kst < 16; ++kst)
        bfr[nt][kst] = *(const bf16x8*)(rp + ((kst * 32 + h * 16) ^ swz));
    }
  }

  f32x16 pacc[2];
#pragma unroll
  for (int nt = 0; nt < 2; ++nt)
#pragma unroll
    for (int q = 0; q < 16; ++q) pacc[nt][q] = 0.f;

  const char* Asrc = refb + ((size_t)(b * RTOT + rs * RPB)) * 512;

  // A-read LDS base pointers: addr = apk[kst&3] + (kst>>2)*128 + bufOFS
  const char* apk[4];
#pragma unroll
  for (int j = 0; j < 4; ++j)
    apk[j] = &Ash[0][(rh * 32 + l31) * 512 + ((j * 32 + h * 16) ^ swz)];

  auto stage = [&](const char* s, char* dbuf) {
#pragma unroll
    for (int i2 = 0; i2 < 8; ++i2) {
      const int seg = i2 * 4 + w;
      async16(s + seg * 1024 + lane * 16, dbuf + seg * 1024);
    }
  };
  // QK^T: 32 MFMA 32x32x16 per chunk per wave; acc init = C0 (bias baked in)
  auto qk = [&](f32x16 (&acc)[2], const int OFS) {
#pragma unroll
    for (int nt = 0; nt < 2; ++nt)
#pragma unroll
      for (int q = 0; q < 16; ++q) acc[nt][q] = C0f;
    __builtin_amdgcn_s_setprio(1);
#pragma unroll
    for (int kst = 0; kst < 16; ++kst) {
      const bf16x8 af = *(const bf16x8*)(apk[kst & 3] + (kst >> 2) * 128 + OFS);
      acc[0] = __builtin_amdgcn_mfma_f32_32x32x16_bf16(af, bfr[0][kst], acc[0], 0, 0, 0);
      acc[1] = __builtin_amdgcn_mfma_f32_32x32x16_bf16(af, bfr[1][kst], acc[1], 0, 0, 0);
    }
    __builtin_amdgcn_s_setprio(0);
  };
  // exp + pack + PV: P = exp2(acc); PV#1 consumes acc regs 0..7 (r-slots via sigma),
  // PV#2 regs 8..15. Labels one-hot built with the same sigma map.
  auto pv = [&](const f32x16 (&acc)[2],
                unsigned wc0, unsigned wc1, unsigned wc2, unsigned wc3) {
    union { bf16x8 v; unsigned u[4]; } lf1, lf2;
    lf1.u[0] = oh2(wc0, l31);       lf1.u[1] = oh2(wc0 >> 16, l31);
    lf1.u[2] = oh2(wc1, l31);       lf1.u[3] = oh2(wc1 >> 16, l31);
    lf2.u[0] = oh2(wc2, l31);       lf2.u[1] = oh2(wc2 >> 16, l31);
    lf2.u[2] = oh2(wc3, l31);       lf2.u[3] = oh2(wc3 >> 16, l31);
#pragma unroll
    for (int nt = 0; nt < 2; ++nt) {
      union { bf16x8 v; unsigned u[4]; } pf;
      {
        float p0 = __builtin_amdgcn_exp2f(acc[nt][0]);
        float p1 = __builtin_amdgcn_exp2f(acc[nt][1]);
        float p2 = __builtin_amdgcn_exp2f(acc[nt][2]);
        float p3 = __builtin_amdgcn_exp2f(acc[nt][3]);
        float p4 = __builtin_amdgcn_exp2f(acc[nt][4]);
        float p5 = __builtin_amdgcn_exp2f(acc[nt][5]);
        float p6 = __builtin_amdgcn_exp2f(acc[nt][6]);
        float p7 = __builtin_amdgcn_exp2f(acc[nt][7]);
        pf.u[0] = cvtpk(p0, p1); pf.u[1] = cvtpk(p2, p3);
        pf.u[2] = cvtpk(p4, p5); pf.u[3] = cvtpk(p6, p7);
      }
      pacc[nt] = __builtin_amdgcn_mfma_f32_32x32x16_bf16(lf1.v, pf.v, pacc[nt], 0, 0, 0);
      {
        float p0 = __builtin_amdgcn_exp2f(acc[nt][8]);
        float p1 = __builtin_amdgcn_exp2f(acc[nt][9]);
        float p2 = __builtin_amdgcn_exp2f(acc[nt][10]);
        float p3 = __builtin_amdgcn_exp2f(acc[nt][11]);
        float p4 = __builtin_amdgcn_exp2f(acc[nt][12]);
        float p5 = __builtin_amdgcn_exp2f(acc[nt][13]);
        float p6 = __builtin_amdgcn_exp2f(acc[nt][14]);
        float p7 = __builtin_amdgcn_exp2f(acc[nt][15]);
        pf.u[0] = cvtpk(p0, p1); pf.u[1] = cvtpk(p2, p3);
        pf.u[2] = cvtpk(p4, p5); pf.u[3] = cvtpk(p6, p7);
      }
      pacc[nt] = __builtin_amdgcn_mfma_f32_32x32x16_bf16(lf2.v, pf.v, pacc[nt], 0, 0, 0);
    }
  };

  f32x16 acc[2];
  // label stream: words at +0,+8,+16,+24 within the wave's 32-r window (h*4 folded in)
  const unsigned char* lcur = lab8 + b * RTOT + rs * RPB + rh * 32 + h * 4;
  unsigned wc0 = *(const unsigned*)(lcur + 0);
  unsigned wc1 = *(const unsigned*)(lcur + 8);
  unsigned wc2 = *(const unsigned*)(lcur + 16);
  unsigned wc3 = *(const unsigned*)(lcur + 24);
  lcur += RR;

  stage(Asrc, &Ash[0][0]);               // prologue: chunk 0 -> buf0
  const char* Acur = Asrc + RR * 512;

#pragma unroll 1
  for (int i = 0; i < 11; ++i) {
    {   // even chunk (buf0): stage next -> buf1
      __syncthreads();                   // drain DMA(cur); readers of buf1 done
      stage(Acur, &Ash[1][0]); Acur += RR * 512;
      qk(acc, 0);
      const unsigned n0 = *(const unsigned*)(lcur + 0);
      const unsigned n1 = *(const unsigned*)(lcur + 8);
      const unsigned n2 = *(const unsigned*)(lcur + 16);
      const unsigned n3 = *(const unsigned*)(lcur + 24);
      lcur += RR;
      pv(acc, wc0, wc1, wc2, wc3);
      wc0 = n0; wc1 = n1; wc2 = n2; wc3 = n3;
    }
    {   // odd chunk (buf1): stage next -> buf0
      __syncthreads();
      stage(Acur, &Ash[0][0]); Acur += RR * 512;
      qk(acc, 32768);
      const unsigned n0 = *(const unsigned*)(lcur + 0);
      const unsigned n1 = *(const unsigned*)(lcur + 8);
      const unsigned n2 = *(const unsigned*)(lcur + 16);
      const unsigned n3 = *(const unsigned*)(lcur + 24);
      lcur += RR;
      pv(acc, wc0, wc1, wc2, wc3);
      wc0 = n0; wc1 = n1; wc2 = n2; wc3 = n3;
    }
  }
  {   // chunk 22 (even, buf0): stage 23 -> buf1
    __syncthreads();
    stage(Acur, &Ash[1][0]);
    qk(acc, 0);
    const unsigned n0 = *(const unsigned*)(lcur + 0);
    const unsigned n1 = *(const unsigned*)(lcur + 8);
    const unsigned n2 = *(const unsigned*)(lcur + 16);
    const unsigned n3 = *(const unsigned*)(lcur + 24);
    pv(acc, wc0, wc1, wc2, wc3);
    wc0 = n0; wc1 = n1; wc2 = n2; wc3 = n3;
  }
  {   // chunk 23 (odd, buf1): no stage, no label prefetch
    __syncthreads();
    qk(acc, 32768);
    pv(acc, wc0, wc1, wc2, wc3);
  }

  // ---- cross-wave reduction of rh partials, then global write of d<10 ----
  __syncthreads();                       // everyone done with Ash (no DMA pending)
  float* sc = (float*)&Ash[0][0];        // 16 KB scratch
  if (rh == 1) {
#pragma unroll
    for (int nt = 0; nt < 2; ++nt)
#pragma unroll
      for (int i4 = 0; i4 < 4; ++i4) {
        f32x4 v4;
        v4[0] = pacc[nt][i4 * 4 + 0]; v4[1] = pacc[nt][i4 * 4 + 1];
        v4[2] = pacc[nt][i4 * 4 + 2]; v4[3] = pacc[nt][i4 * 4 + 3];
        *(f32x4*)&sc[(th * 64 + lane) * 32 + nt * 16 + i4 * 4] = v4;
      }
  }
  __syncthreads();
  if (rh == 0) {
#pragma unroll
    for (int nt = 0; nt < 2; ++nt) {
#pragma unroll
      for (int i4 = 0; i4 < 4; ++i4) {
        const f32x4 v4 = *(const f32x4*)&sc[(th * 64 + lane) * 32 + nt * 16 + i4 * 4];
        pacc[nt][i4 * 4 + 0] += v4[0]; pacc[nt][i4 * 4 + 1] += v4[1];
        pacc[nt][i4 * 4 + 2] += v4[2]; pacc[nt][i4 * 4 + 3] += v4[3];
      }
      // lane (t = th*64+nt*32+l31, h): valid d: h=0 -> q0..3=d0..3, q4,5=d8,9;
      //                                h=1 -> q0..3=d4..7
      const int t = th * 64 + nt * 32 + l31;
      float* base = pred + (((size_t)(rs * B_ + b)) * HW + (size_t)tb * TT + t) * 16;
      f32x4 v4;
      v4[0] = pacc[nt][0]; v4[1] = pacc[nt][1];
      v4[2] = pacc[nt][2]; v4[3] = pacc[nt][3];
      if (h == 0) {
        *(f32x4*)(base + 0) = v4;
        float2 v2; v2.x = pacc[nt][4]; v2.y = pacc[nt][5];
        *(float2*)(base + 8) = v2;
      } else {
        *(f32x4*)(base + 4) = v4;
      }
    }
  }
}

// ---------------- kernel 3: per-pixel loss terms + block reduce ----------------
__global__ __launch_bounds__(256) void k_epi(const float* __restrict__ pred,
                                             const int* __restrict__ tl,
                                             float* __restrict__ red) {
  const int idx = blockIdx.x * 256 + threadIdx.x;   // < 8192
  const int b = idx >> 12, t = idx & 4095;
  union { f32x4 v[3]; float f[12]; } S;
  S.v[0] = f32x4{0.f, 0.f, 0.f, 0.f};
  S.v[1] = f32x4{0.f, 0.f, 0.f, 0.f};
  S.v[2] = f32x4{0.f, 0.f, 0.f, 0.f};
#pragma unroll
  for (int r = 0; r < RS; ++r) {
    const f32x4* p = (const f32x4*)&pred[(((size_t)(r * B_ + b)) * HW + t) * 16];
    S.v[0] += p[0]; S.v[1] += p[1]; S.v[2] += p[2];
  }
  float T = 0.f;
#pragma unroll
  for (int d = 0; d < DCLS; ++d) T += S.f[d];
  const float inv = 1.f / T;
  const int lb = tl[idx];
  float se = 0.f, zt = 0.f;
#pragma unroll
  for (int d = 0; d < DCLS; ++d) {
    const float z = S.f[d] * inv;      // pred prob in [0,1]
    se += __expf(z);
    if (d == lb) zt = z;
  }
  const float logpt = zt - __logf(se);
  const float pt = __expf(zt) / se;
  const float focal = sqrtf(fmaxf(1.f - pt, 0.f));   // gamma = 0.5

  float lp = logpt, fo = focal;
#pragma unroll
  for (int off = 32; off; off >>= 1) {
    lp += __shfl_down(lp, off);
    fo += __shfl_down(fo, off);
  }
  __shared__ float rb_[8];
  const int lane = threadIdx.x & 63, wv = threadIdx.x >> 6;
  if (lane == 0) { rb_[wv] = lp; rb_[4 + wv] = fo; }
  __syncthreads();
  if (threadIdx.x == 0) {
    red[blockIdx.x * 2 + 0] = rb_[0] + rb_[1] + rb_[2] + rb_[3];
    red[blockIdx.x * 2 + 1] = rb_[4] + rb_[5] + rb_[6] + rb_[7];
  }
}

// ---------------- kernel 4: final scalar ----------------
__global__ void k_fin(const float* __restrict__ red, float* __restrict__ out) {
  const int tid = threadIdx.x;   // 64
  float lp = 0.f, fo = 0.f;
  if (tid < 32) { lp = red[tid * 2]; fo = red[tid * 2 + 1]; }
#pragma unroll
  for (int off = 16; off; off >>= 1) {
    lp += __shfl_down(lp, off);
    fo += __shfl_down(fo, off);
  }
  if (tid == 0) {
    const float ce = -lp / (float)NPIX;       // ce = -mean(log_pt)
    out[0] = ce * (fo / (float)NPIX);         // loss = ce * mean(focal)
  }
}

extern "C" void kernel_launch(void* const* d_in, const int* in_sizes, int n_in,
                              void* d_out, int out_size, void* d_ws, size_t ws_size,
                              hipStream_t stream)
{
  const float* ref  = (const float*)d_in[0];
  const float* tgt  = (const float*)d_in[1];
  const float* rl   = (const float*)d_in[2];
  const int*   tlab = (const int*)d_in[3];
  float* out = (float*)d_out;

  char* ws = (char*)d_ws;
  char* refb = ws;                                    // 32768 rows * 512 B = 16 MB (ref + tgt)
  char* tgtb = ws + (size_t)24576 * 512;              // tgt rows start at 24576
  unsigned char* lab8 = (unsigned char*)(ws + 16777216);          // 24 KB (pad 32 KB)
  float* pred = (float*)(ws + 16777216 + 32768);                  // 4 MB (RS*B*HW*16 f32)
  float* red  = (float*)(ws + 16777216 + 32768 + 4194304);        // 256 B

  k_pre<<<352, 256, 0, stream>>>(ref, tgt, rl, refb, lab8);
  k_main<<<512, 256, 0, stream>>>(refb, tgtb, lab8, pred);
  k_epi<<<32, 256, 0, stream>>>(pred, tlab, red);
  k_fin<<<1, 64, 0, stream>>>(red, out);
}

// Round 8
// 78.902 us; speedup vs baseline: 1.0594x; 1.0594x over previous
//
#include <hip/hip_runtime.h>
#include <hip/hip_bf16.h>
#include <stdint.h>
#include <stddef.h>

// Problem constants
#define B_    2
#define NREF  3
#define FDIM  256
#define HW    4096
#define DCLS  10
#define RTOT  12288          // NREF*HW reference pixels per batch
#define TT    128            // target pixels per block (4 waves)
#define RR    64             // reference pixels per chunk
#define RS    8              // r-axis split across blocks
#define RPB   1536           // RTOT/RS
#define NCH   24             // RPB/RR
#define NPIX  8192           // B_*HW
#define LOG2E 1.44269504f
#define C0f   (-144.269504f)  // -100*LOG2E; QK acc init so acc = sim*log2e - 100*log2e

typedef __attribute__((ext_vector_type(8))) short bf16x8;
typedef __attribute__((ext_vector_type(4))) float f32x4;
typedef __attribute__((ext_vector_type(4))) unsigned int u32x4;

__device__ __forceinline__ unsigned short f2bf(float x) {
  union { float f; unsigned u; } v; v.f = x;
  unsigned r = v.u + 0x7fffu + ((v.u >> 16) & 1u);   // RNE
  return (unsigned short)(r >> 16);
}
__device__ __forceinline__ unsigned pk2(float a, float b) {
  return (unsigned)f2bf(a) | ((unsigned)f2bf(b) << 16);
}
// single-instruction packed f32->bf16 (RNE), gfx950
__device__ __forceinline__ unsigned cvtpk(float a, float b) {
  unsigned r;
  asm("v_cvt_pk_bf16_f32 %0, %1, %2" : "=v"(r) : "v"(a), "v"(b));
  return r;
}
// async global->LDS, 16B per lane; LDS dest is wave-uniform base + lane*16
__device__ __forceinline__ void async16(const void* g, void* l) {
  __builtin_amdgcn_global_load_lds(
      (const __attribute__((address_space(1))) void*)g,
      (__attribute__((address_space(3))) void*)l, 16, 0, 0);
}
// one-hot pair: low/high 16-bit bf16 1.0 where label byte matches d=l15
__device__ __forceinline__ unsigned oh2(unsigned word, int d) {
  return ((word & 255u) == (unsigned)d ? 0x3F80u : 0u) |
         (((word >> 8) & 255u) == (unsigned)d ? 0x3F800000u : 0u);
}

// ---------------- kernel 1: fused prep (transpose+convert) + label extract ----------------
// blocks [0,256): ref/tgt -> bf16 rows of 512B with XOR swizzle baked per row.
// ref rows pre-scaled by LOG2E (QK comes out in log2 units; -100*log2e via acc init).
__global__ __launch_bounds__(256) void k_pre(const float* __restrict__ ref,
                                             const float* __restrict__ tgt,
                                             const float* __restrict__ rl,
                                             char* __restrict__ outb,
                                             unsigned char* __restrict__ lab8) {
  const int tid = threadIdx.x;
  if (blockIdx.x < 256) {
    const int row = blockIdx.x * 128 + (tid & 127);   // row 0..32767
    const int half = tid >> 7;
    const float* src;
    float scl;
    if (row < B_ * RTOT) {
      const int b = row / RTOT, rr2 = row % RTOT;
      src = ref + ((size_t)(b * NREF + (rr2 >> 12)) * FDIM) * HW + (rr2 & 4095);
      scl = LOG2E;
    } else {
      const int r2 = row - B_ * RTOT;
      src = tgt + ((size_t)(r2 >> 12) * FDIM) * HW + (r2 & 4095);
      scl = 1.0f;
    }
    char* dst = outb + (size_t)row * 512;
    const int sw = (row & 7) << 4;
    for (int ci = 0; ci < 16; ++ci) {
      const int c16 = half * 16 + ci;
      float v[8];
#pragma unroll
      for (int j = 0; j < 8; ++j) v[j] = src[(size_t)(c16 * 8 + j) * HW] * scl;
      u32x4 u;
      u[0] = pk2(v[0], v[1]); u[1] = pk2(v[2], v[3]);
      u[2] = pk2(v[4], v[5]); u[3] = pk2(v[6], v[7]);
      *(u32x4*)(dst + ((c16 * 16) ^ sw)) = u;
    }
  } else {
    const int idx = (blockIdx.x - 256) * 256 + tid;   // < 24576
    if (idx >= B_ * RTOT) return;
    const int b = idx / RTOT, r = idx % RTOT;
    const float* p = rl + ((size_t)((b * NREF + (r >> 12)) * DCLS)) * HW + (r & 4095);
    int v = 0;
#pragma unroll
    for (int d = 1; d < DCLS; ++d)
      if (p[(size_t)d * HW] > 0.5f) v = d;
    lab8[idx] = (unsigned char)v;
  }
}

// ---------------- kernel 2: fused QK-softmax-PV (16x16x32 MFMA, 8 acc chains) ----------------
// grid = RS(8) * 32(tblocks) * B_(2) = 512 blocks of 256 threads, 2 blocks/CU.
// Round-6 geometry (verified 54.4us) + round-7 VALU path (C0 acc-init, exp2-only pv).
__global__ __launch_bounds__(256, 2) void k_main(const char* __restrict__ refb,
                                                 const char* __restrict__ tgtb,
                                                 const unsigned char* __restrict__ lab8,
                                                 float* __restrict__ pred) {
  __shared__ __align__(16) char Ash[2][RR * 512];   // double-buffered ref chunk, 64 KB

  const int tid = threadIdx.x;
  const int lane = tid & 63;
  const int w = tid >> 6;                // wave 0..3
  const int l15 = lane & 15, l4 = lane >> 4;
  const int rh = w >> 1, th = w & 1;     // wave sub-tile: 32r x 64t
  const int swz = (l15 & 7) << 4;

  const int bid = blockIdx.x;
  const int rs = bid & 7;
  const int tb = (bid >> 3) & 31;
  const int b  = bid >> 8;

  // ---- B fragments in registers: wave's 64 t x full K=256 (128 VGPR) ----
  bf16x8 bfr[4][8];
  {
    const char* base = tgtb + ((size_t)(b * HW + tb * TT + th * 64)) * 512;
#pragma unroll
    for (int nt = 0; nt < 4; ++nt) {
      const char* rp = base + (size_t)((nt * 16 + l15) * 512);
#pragma unroll
      for (int ks = 0; ks < 8; ++ks)
        bfr[nt][ks] = *(const bf16x8*)(rp + ((ks * 64 + l4 * 16) ^ swz));
    }
  }

  f32x4 pacc[4];
#pragma unroll
  for (int i = 0; i < 4; ++i) pacc[i] = f32x4{0.f, 0.f, 0.f, 0.f};

  const char* Asrc = refb + ((size_t)(b * RTOT + rs * RPB)) * 512;

  // precomputed A-read base pointers (buf0); buf1 reached via +32768 immediate
  const char* ap00 = &Ash[0][(rh * 32 +  0 + l15) * 512 + ((     l4 * 16) ^ swz)];
  const char* ap01 = &Ash[0][(rh * 32 +  0 + l15) * 512 + ((64 + l4 * 16) ^ swz)];
  const char* ap10 = &Ash[0][(rh * 32 + 16 + l15) * 512 + ((     l4 * 16) ^ swz)];
  const char* ap11 = &Ash[0][(rh * 32 + 16 + l15) * 512 + ((64 + l4 * 16) ^ swz)];

  // stage chunk at src -> dbuf (32 segs of 1 KB, 8 per wave)
  auto stage = [&](const char* s, char* dbuf) {
#pragma unroll
    for (int i2 = 0; i2 < 8; ++i2) {
      const int seg = i2 * 4 + w;
      async16(s + seg * 1024 + lane * 16, dbuf + seg * 1024);
    }
  };
  // QK^T of one chunk: 64 MFMA/wave; A via precomputed addrs + immediates.
  // acc init = C0f (exp bias baked into the matmul's C operand).
  auto qk = [&](f32x4 (&acc)[2][4], const int OFS) {
#pragma unroll
    for (int i2 = 0; i2 < 2; ++i2)
#pragma unroll
      for (int j = 0; j < 4; ++j) acc[i2][j] = f32x4{C0f, C0f, C0f, C0f};
    __builtin_amdgcn_s_setprio(1);
#pragma unroll
    for (int ks = 0; ks < 8; ++ks) {
      const int ko = OFS + (ks >> 1) * 128;
      const bf16x8 af0 = *(const bf16x8*)(((ks & 1) ? ap01 : ap00) + ko);
      const bf16x8 af1 = *(const bf16x8*)(((ks & 1) ? ap11 : ap10) + ko);
#pragma unroll
      for (int nt = 0; nt < 4; ++nt)
        acc[0][nt] = __builtin_amdgcn_mfma_f32_16x16x32_bf16(
            af0, bfr[nt][ks], acc[0][nt], 0, 0, 0);
#pragma unroll
      for (int nt = 0; nt < 4; ++nt)
        acc[1][nt] = __builtin_amdgcn_mfma_f32_16x16x32_bf16(
            af1, bfr[nt][ks], acc[1][nt], 0, 0, 0);
    }
    __builtin_amdgcn_s_setprio(0);
  };
  // exp2 + pack + PV (wave-local; acc reg layout IS the PV B-frag layout)
  auto pv = [&](const f32x4 (&acc)[2][4], unsigned la, unsigned lb2) {
    union { bf16x8 v; unsigned u[4]; } lf;
    lf.u[0] = oh2(la, l15);        lf.u[1] = oh2(la >> 16, l15);
    lf.u[2] = oh2(lb2, l15);       lf.u[3] = oh2(lb2 >> 16, l15);
#pragma unroll
    for (int nt = 0; nt < 4; ++nt) {
      const f32x4 a0 = acc[0][nt], a1 = acc[1][nt];
      float p0 = __builtin_amdgcn_exp2f(a0[0]);
      float p1 = __builtin_amdgcn_exp2f(a0[1]);
      float p2 = __builtin_amdgcn_exp2f(a0[2]);
      float p3 = __builtin_amdgcn_exp2f(a0[3]);
      float p4 = __builtin_amdgcn_exp2f(a1[0]);
      float p5 = __builtin_amdgcn_exp2f(a1[1]);
      float p6 = __builtin_amdgcn_exp2f(a1[2]);
      float p7 = __builtin_amdgcn_exp2f(a1[3]);
      union { bf16x8 v; unsigned u[4]; } pf;
      pf.u[0] = cvtpk(p0, p1); pf.u[1] = cvtpk(p2, p3);
      pf.u[2] = cvtpk(p4, p5); pf.u[3] = cvtpk(p6, p7);
      pacc[nt] = __builtin_amdgcn_mfma_f32_16x16x32_bf16(lf.v, pf.v, pacc[nt], 0, 0, 0);
    }
  };

  f32x4 acc[2][4];
  const unsigned char* lbp = lab8 + b * RTOT + rs * RPB + rh * 32 + l4 * 4;
  const char* Acur = Asrc + RR * 512;    // global source of the NEXT chunk

  stage(Asrc, &Ash[0][0]);               // prologue: chunk 0 -> buf0

#pragma unroll 1
  for (int i = 0; i < 11; ++i) {
    {   // even chunk (buf0): stage next -> buf1
      const unsigned la  = *(const unsigned*)lbp;
      const unsigned l2_ = *(const unsigned*)(lbp + 16);
      __syncthreads();                   // drain DMA(cur); readers of buf1 done
      stage(Acur, &Ash[1][0]); Acur += RR * 512;
      qk(acc, 0);
      pv(acc, la, l2_);
      lbp += RR;
    }
    {   // odd chunk (buf1): stage next -> buf0
      const unsigned la  = *(const unsigned*)lbp;
      const unsigned l2_ = *(const unsigned*)(lbp + 16);
      __syncthreads();
      stage(Acur, &Ash[0][0]); Acur += RR * 512;
      qk(acc, 32768);
      pv(acc, la, l2_);
      lbp += RR;
    }
  }
  {   // chunk 22 (even, buf0): stage 23 -> buf1
    const unsigned la  = *(const unsigned*)lbp;
    const unsigned l2_ = *(const unsigned*)(lbp + 16);
    __syncthreads();
    stage(Acur, &Ash[1][0]);
    qk(acc, 0);
    pv(acc, la, l2_);
    lbp += RR;
  }
  {   // chunk 23 (odd, buf1): no stage
    const unsigned la  = *(const unsigned*)lbp;
    const unsigned l2_ = *(const unsigned*)(lbp + 16);
    __syncthreads();
    qk(acc, 32768);
    pv(acc, la, l2_);
  }

  // ---- cross-wave reduction of rh partials (once), then global write ----
  __syncthreads();                       // everyone done with Ash (no DMA pending)
  float* sc = (float*)&Ash[0][0];        // 8 KB scratch
  if (rh == 1) {
#pragma unroll
    for (int nt = 0; nt < 4; ++nt)
      *(f32x4*)&sc[((th * 64 + lane) * 4 + nt) * 4] = pacc[nt];
  }
  __syncthreads();
  if (rh == 0) {
#pragma unroll
    for (int nt = 0; nt < 4; ++nt) {
      pacc[nt] += *(const f32x4*)&sc[((th * 64 + lane) * 4 + nt) * 4];
      const int t = th * 64 + nt * 16 + l15;
      const size_t o = (((size_t)(rs * B_ + b)) * HW + (size_t)tb * TT + t) * 16 + l4 * 4;
      *(f32x4*)&pred[o] = pacc[nt];
    }
  }
}

// ---------------- kernel 3: per-pixel loss terms + block reduce ----------------
__global__ __launch_bounds__(256) void k_epi(const float* __restrict__ pred,
                                             const int* __restrict__ tl,
                                             float* __restrict__ red) {
  const int idx = blockIdx.x * 256 + threadIdx.x;   // < 8192
  const int b = idx >> 12, t = idx & 4095;
  union { f32x4 v[3]; float f[12]; } S;
  S.v[0] = f32x4{0.f, 0.f, 0.f, 0.f};
  S.v[1] = f32x4{0.f, 0.f, 0.f, 0.f};
  S.v[2] = f32x4{0.f, 0.f, 0.f, 0.f};
#pragma unroll
  for (int r = 0; r < RS; ++r) {
    const f32x4* p = (const f32x4*)&pred[(((size_t)(r * B_ + b)) * HW + t) * 16];
    S.v[0] += p[0]; S.v[1] += p[1]; S.v[2] += p[2];
  }
  float T = 0.f;
#pragma unroll
  for (int d = 0; d < DCLS; ++d) T += S.f[d];
  const float inv = 1.f / T;
  const int lb = tl[idx];
  float se = 0.f, zt = 0.f;
#pragma unroll
  for (int d = 0; d < DCLS; ++d) {
    const float z = S.f[d] * inv;      // pred prob in [0,1]
    se += __expf(z);
    if (d == lb) zt = z;
  }
  const float logpt = zt - __logf(se);
  const float pt = __expf(zt) / se;
  const float focal = sqrtf(fmaxf(1.f - pt, 0.f));   // gamma = 0.5

  float lp = logpt, fo = focal;
#pragma unroll
  for (int off = 32; off; off >>= 1) {
    lp += __shfl_down(lp, off);
    fo += __shfl_down(fo, off);
  }
  __shared__ float rb_[8];
  const int lane = threadIdx.x & 63, wv = threadIdx.x >> 6;
  if (lane == 0) { rb_[wv] = lp; rb_[4 + wv] = fo; }
  __syncthreads();
  if (threadIdx.x == 0) {
    red[blockIdx.x * 2 + 0] = rb_[0] + rb_[1] + rb_[2] + rb_[3];
    red[blockIdx.x * 2 + 1] = rb_[4] + rb_[5] + rb_[6] + rb_[7];
  }
}

// ---------------- kernel 4: final scalar ----------------
__global__ void k_fin(const float* __restrict__ red, float* __restrict__ out) {
  const int tid = threadIdx.x;   // 64
  float lp = 0.f, fo = 0.f;
  if (tid < 32) { lp = red[tid * 2]; fo = red[tid * 2 + 1]; }
#pragma unroll
  for (int off = 16; off; off >>= 1) {
    lp += __shfl_down(lp, off);
    fo += __shfl_down(fo, off);
  }
  if (tid == 0) {
    const float ce = -lp / (float)NPIX;       // ce = -mean(log_pt)
    out[0] = ce * (fo / (float)NPIX);         // loss = ce * mean(focal)
  }
}

extern "C" void kernel_launch(void* const* d_in, const int* in_sizes, int n_in,
                              void* d_out, int out_size, void* d_ws, size_t ws_size,
                              hipStream_t stream)
{
  const float* ref  = (const float*)d_in[0];
  const float* tgt  = (const float*)d_in[1];
  const float* rl   = (const float*)d_in[2];
  const int*   tlab = (const int*)d_in[3];
  float* out = (float*)d_out;

  char* ws = (char*)d_ws;
  char* refb = ws;                                    // 32768 rows * 512 B = 16 MB (ref + tgt)
  char* tgtb = ws + (size_t)24576 * 512;              // tgt rows start at 24576
  unsigned char* lab8 = (unsigned char*)(ws + 16777216);          // 24 KB (pad 32 KB)
  float* pred = (float*)(ws + 16777216 + 32768);                  // 4 MB (RS*B*HW*16 f32)
  float* red  = (float*)(ws + 16777216 + 32768 + 4194304);        // 256 B

  k_pre<<<352, 256, 0, stream>>>(ref, tgt, rl, refb, lab8);
  k_main<<<512, 256, 0, stream>>>(refb, tgtb, lab8, pred);
  k_epi<<<32, 256, 0, stream>>>(pred, tlab, red);
  k_fin<<<1, 64, 0, stream>>>(red, out);
}

// Round 9
// 76.538 us; speedup vs baseline: 1.0922x; 1.0309x over previous
//
#include <hip/hip_runtime.h>
#include <hip/hip_bf16.h>
#include <stdint.h>
#include <stddef.h>

// Problem constants
#define B_    2
#define NREF  3
#define FDIM  256
#define HW    4096
#define DCLS  10
#define RTOT  12288          // NREF*HW reference pixels per batch
#define TT    128            // target pixels per block (4 waves)
#define RR    64             // reference pixels per chunk
#define RS    8              // r-axis split across blocks
#define RPB   1536           // RTOT/RS
#define NCH   24             // RPB/RR
#define NPIX  8192           // B_*HW
#define LOG2E 1.44269504f
#define C0f   (-144.269504f)  // -100*LOG2E; QK acc init so acc = sim*log2e - 100*log2e

typedef __attribute__((ext_vector_type(8))) short bf16x8;
typedef __attribute__((ext_vector_type(4))) float f32x4;
typedef __attribute__((ext_vector_type(4))) unsigned int u32x4;

__device__ __forceinline__ unsigned short f2bf(float x) {
  union { float f; unsigned u; } v; v.f = x;
  unsigned r = v.u + 0x7fffu + ((v.u >> 16) & 1u);   // RNE
  return (unsigned short)(r >> 16);
}
__device__ __forceinline__ unsigned pk2(float a, float b) {
  return (unsigned)f2bf(a) | ((unsigned)f2bf(b) << 16);
}
// single-instruction packed f32->bf16 (RNE), gfx950
__device__ __forceinline__ unsigned cvtpk(float a, float b) {
  unsigned r;
  asm("v_cvt_pk_bf16_f32 %0, %1, %2" : "=v"(r) : "v"(a), "v"(b));
  return r;
}
// async global->LDS, 16B per lane; LDS dest is wave-uniform base + lane*16
__device__ __forceinline__ void async16(const void* g, void* l) {
  __builtin_amdgcn_global_load_lds(
      (const __attribute__((address_space(1))) void*)g,
      (__attribute__((address_space(3))) void*)l, 16, 0, 0);
}
// one-hot pair: low/high 16-bit bf16 1.0 where label byte matches d=l15
__device__ __forceinline__ unsigned oh2(unsigned word, int d) {
  return ((word & 255u) == (unsigned)d ? 0x3F80u : 0u) |
         (((word >> 8) & 255u) == (unsigned)d ? 0x3F800000u : 0u);
}

// ---------------- kernel 1: fused prep (transpose+convert) + label extract ----------------
// blocks [0,256): ref/tgt -> bf16 rows of 512B with XOR swizzle baked per row.
// ref rows pre-scaled by LOG2E (QK comes out in log2 units; -100*log2e via acc init).
__global__ __launch_bounds__(256) void k_pre(const float* __restrict__ ref,
                                             const float* __restrict__ tgt,
                                             const float* __restrict__ rl,
                                             char* __restrict__ outb,
                                             unsigned char* __restrict__ lab8) {
  const int tid = threadIdx.x;
  if (blockIdx.x < 256) {
    const int row = blockIdx.x * 128 + (tid & 127);   // row 0..32767
    const int half = tid >> 7;
    const float* src;
    float scl;
    if (row < B_ * RTOT) {
      const int b = row / RTOT, rr2 = row % RTOT;
      src = ref + ((size_t)(b * NREF + (rr2 >> 12)) * FDIM) * HW + (rr2 & 4095);
      scl = LOG2E;
    } else {
      const int r2 = row - B_ * RTOT;
      src = tgt + ((size_t)(r2 >> 12) * FDIM) * HW + (r2 & 4095);
      scl = 1.0f;
    }
    char* dst = outb + (size_t)row * 512;
    const int sw = (row & 7) << 4;
    for (int ci = 0; ci < 16; ++ci) {
      const int c16 = half * 16 + ci;
      float v[8];
#pragma unroll
      for (int j = 0; j < 8; ++j) v[j] = src[(size_t)(c16 * 8 + j) * HW] * scl;
      u32x4 u;
      u[0] = pk2(v[0], v[1]); u[1] = pk2(v[2], v[3]);
      u[2] = pk2(v[4], v[5]); u[3] = pk2(v[6], v[7]);
      *(u32x4*)(dst + ((c16 * 16) ^ sw)) = u;
    }
  } else {
    const int idx = (blockIdx.x - 256) * 256 + tid;   // < 24576
    if (idx >= B_ * RTOT) return;
    const int b = idx / RTOT, r = idx % RTOT;
    const float* p = rl + ((size_t)((b * NREF + (r >> 12)) * DCLS)) * HW + (r & 4095);
    int v = 0;
#pragma unroll
    for (int d = 1; d < DCLS; ++d)
      if (p[(size_t)d * HW] > 0.5f) v = d;
    lab8[idx] = (unsigned char)v;
  }
}

// ---------------- kernel 2: fused QK-softmax-PV (16x16x32, pv deferred one step) ----------------
// grid = RS(8) * 32(tblocks) * B_(2) = 512 blocks of 256 threads, 2 blocks/CU.
// Per chunk step: barrier; stage(c+1); pv(acc of c-1) [regs only, legal across
// the barrier]; qk(acc, c). pv's exp/cvtpk VALU work fills the post-barrier
// ds_read warmup and MFMA ramp of qk; single acc set (WAR handled by scheduler,
// no extra acc registers -> no round-5 spill).
__global__ __launch_bounds__(256, 2) void k_main(const char* __restrict__ refb,
                                                 const char* __restrict__ tgtb,
                                                 const unsigned char* __restrict__ lab8,
                                                 float* __restrict__ pred) {
  __shared__ __align__(16) char Ash[2][RR * 512];   // double-buffered ref chunk, 64 KB

  const int tid = threadIdx.x;
  const int lane = tid & 63;
  const int w = tid >> 6;                // wave 0..3
  const int l15 = lane & 15, l4 = lane >> 4;
  const int rh = w >> 1, th = w & 1;     // wave sub-tile: 32r x 64t
  const int swz = (l15 & 7) << 4;

  const int bid = blockIdx.x;
  const int rs = bid & 7;
  const int tb = (bid >> 3) & 31;
  const int b  = bid >> 8;

  // ---- B fragments in registers: wave's 64 t x full K=256 (128 VGPR) ----
  bf16x8 bfr[4][8];
  {
    const char* base = tgtb + ((size_t)(b * HW + tb * TT + th * 64)) * 512;
#pragma unroll
    for (int nt = 0; nt < 4; ++nt) {
      const char* rp = base + (size_t)((nt * 16 + l15) * 512);
#pragma unroll
      for (int ks = 0; ks < 8; ++ks)
        bfr[nt][ks] = *(const bf16x8*)(rp + ((ks * 64 + l4 * 16) ^ swz));
    }
  }

  f32x4 pacc[4];
#pragma unroll
  for (int i = 0; i < 4; ++i) pacc[i] = f32x4{0.f, 0.f, 0.f, 0.f};

  const char* Asrc = refb + ((size_t)(b * RTOT + rs * RPB)) * 512;

  // precomputed A-read base pointers (buf0); buf1 reached via +32768 immediate
  const char* ap00 = &Ash[0][(rh * 32 +  0 + l15) * 512 + ((     l4 * 16) ^ swz)];
  const char* ap01 = &Ash[0][(rh * 32 +  0 + l15) * 512 + ((64 + l4 * 16) ^ swz)];
  const char* ap10 = &Ash[0][(rh * 32 + 16 + l15) * 512 + ((     l4 * 16) ^ swz)];
  const char* ap11 = &Ash[0][(rh * 32 + 16 + l15) * 512 + ((64 + l4 * 16) ^ swz)];

  // stage chunk at src -> dbuf (32 segs of 1 KB, 8 per wave)
  auto stage = [&](const char* s, char* dbuf) {
#pragma unroll
    for (int i2 = 0; i2 < 8; ++i2) {
      const int seg = i2 * 4 + w;
      async16(s + seg * 1024 + lane * 16, dbuf + seg * 1024);
    }
  };
  // QK^T of one chunk: 64 MFMA/wave; A via precomputed addrs + immediates.
  // acc init = C0f (exp bias baked into the matmul's C operand).
  auto qk = [&](f32x4 (&acc)[2][4], const int OFS) {
#pragma unroll
    for (int i2 = 0; i2 < 2; ++i2)
#pragma unroll
      for (int j = 0; j < 4; ++j) acc[i2][j] = f32x4{C0f, C0f, C0f, C0f};
    __builtin_amdgcn_s_setprio(1);
#pragma unroll
    for (int ks = 0; ks < 8; ++ks) {
      const int ko = OFS + (ks >> 1) * 128;
      const bf16x8 af0 = *(const bf16x8*)(((ks & 1) ? ap01 : ap00) + ko);
      const bf16x8 af1 = *(const bf16x8*)(((ks & 1) ? ap11 : ap10) + ko);
#pragma unroll
      for (int nt = 0; nt < 4; ++nt)
        acc[0][nt] = __builtin_amdgcn_mfma_f32_16x16x32_bf16(
            af0, bfr[nt][ks], acc[0][nt], 0, 0, 0);
#pragma unroll
      for (int nt = 0; nt < 4; ++nt)
        acc[1][nt] = __builtin_amdgcn_mfma_f32_16x16x32_bf16(
            af1, bfr[nt][ks], acc[1][nt], 0, 0, 0);
    }
    __builtin_amdgcn_s_setprio(0);
  };
  // exp2 + pack + PV (wave-local; acc reg layout IS the PV B-frag layout)
  auto pv = [&](const f32x4 (&acc)[2][4], unsigned la, unsigned lb2) {
    union { bf16x8 v; unsigned u[4]; } lf;
    lf.u[0] = oh2(la, l15);        lf.u[1] = oh2(la >> 16, l15);
    lf.u[2] = oh2(lb2, l15);       lf.u[3] = oh2(lb2 >> 16, l15);
#pragma unroll
    for (int nt = 0; nt < 4; ++nt) {
      const f32x4 a0 = acc[0][nt], a1 = acc[1][nt];
      float p0 = __builtin_amdgcn_exp2f(a0[0]);
      float p1 = __builtin_amdgcn_exp2f(a0[1]);
      float p2 = __builtin_amdgcn_exp2f(a0[2]);
      float p3 = __builtin_amdgcn_exp2f(a0[3]);
      float p4 = __builtin_amdgcn_exp2f(a1[0]);
      float p5 = __builtin_amdgcn_exp2f(a1[1]);
      float p6 = __builtin_amdgcn_exp2f(a1[2]);
      float p7 = __builtin_amdgcn_exp2f(a1[3]);
      union { bf16x8 v; unsigned u[4]; } pf;
      pf.u[0] = cvtpk(p0, p1); pf.u[1] = cvtpk(p2, p3);
      pf.u[2] = cvtpk(p4, p5); pf.u[3] = cvtpk(p6, p7);
      pacc[nt] = __builtin_amdgcn_mfma_f32_16x16x32_bf16(lf.v, pf.v, pacc[nt], 0, 0, 0);
    }
  };

  f32x4 acc[2][4];
  const unsigned char* lbp = lab8 + b * RTOT + rs * RPB + rh * 32 + l4 * 4;
  const char* Acur = Asrc + 2 * (RR * 512);   // global source of chunk 2 (next to stage)

  // prologue: labels(0); stage(0)->buf0; drain; stage(1)->buf1; qk(0)
  unsigned la_p = *(const unsigned*)lbp;
  unsigned lb_p = *(const unsigned*)(lbp + 16);
  lbp += RR;
  stage(Asrc, &Ash[0][0]);
  __syncthreads();
  stage(Asrc + RR * 512, &Ash[1][0]);
  qk(acc, 0);

#pragma unroll 1
  for (int i = 0; i < 11; ++i) {
    {   // step: chunk c=1+2i (odd, buf1); stage c+1 -> buf0; pv(c-1)
      const unsigned la_n = *(const unsigned*)lbp;
      const unsigned lb_n = *(const unsigned*)(lbp + 16);
      lbp += RR;
      __syncthreads();                   // drain DMA(c); readers of buf0 done
      stage(Acur, &Ash[0][0]); Acur += RR * 512;
      pv(acc, la_p, lb_p);               // chunk c-1 (regs only)
      qk(acc, 32768);                    // chunk c from buf1
      la_p = la_n; lb_p = lb_n;
    }
    {   // step: chunk c=2+2i (even, buf0); stage c+1 -> buf1; pv(c-1)
      const unsigned la_n = *(const unsigned*)lbp;
      const unsigned lb_n = *(const unsigned*)(lbp + 16);
      lbp += RR;
      __syncthreads();                   // drain DMA(c); readers of buf1 done
      stage(Acur, &Ash[1][0]); Acur += RR * 512;
      pv(acc, la_p, lb_p);               // chunk c-1
      qk(acc, 0);                        // chunk c from buf0
      la_p = la_n; lb_p = lb_n;
    }
  }
  {   // chunk 23 (odd, buf1): no stage; then final pv(23)
    const unsigned la_n = *(const unsigned*)lbp;   // labels(23)
    const unsigned lb_n = *(const unsigned*)(lbp + 16);
    __syncthreads();                     // drain DMA(23)
    pv(acc, la_p, lb_p);                 // chunk 22
    qk(acc, 32768);                      // chunk 23
    pv(acc, la_n, lb_n);                 // chunk 23
  }

  // ---- cross-wave reduction of rh partials (once), then global write ----
  __syncthreads();                       // everyone done with Ash (no DMA pending)
  float* sc = (float*)&Ash[0][0];        // 8 KB scratch
  if (rh == 1) {
#pragma unroll
    for (int nt = 0; nt < 4; ++nt)
      *(f32x4*)&sc[((th * 64 + lane) * 4 + nt) * 4] = pacc[nt];
  }
  __syncthreads();
  if (rh == 0) {
#pragma unroll
    for (int nt = 0; nt < 4; ++nt) {
      pacc[nt] += *(const f32x4*)&sc[((th * 64 + lane) * 4 + nt) * 4];
      const int t = th * 64 + nt * 16 + l15;
      const size_t o = (((size_t)(rs * B_ + b)) * HW + (size_t)tb * TT + t) * 16 + l4 * 4;
      *(f32x4*)&pred[o] = pacc[nt];
    }
  }
}

// ---------------- kernel 3: per-pixel loss terms + block reduce ----------------
__global__ __launch_bounds__(256) void k_epi(const float* __restrict__ pred,
                                             const int* __restrict__ tl,
                                             float* __restrict__ red) {
  const int idx = blockIdx.x * 256 + threadIdx.x;   // < 8192
  const int b = idx >> 12, t = idx & 4095;
  union { f32x4 v[3]; float f[12]; } S;
  S.v[0] = f32x4{0.f, 0.f, 0.f, 0.f};
  S.v[1] = f32x4{0.f, 0.f, 0.f, 0.f};
  S.v[2] = f32x4{0.f, 0.f, 0.f, 0.f};
#pragma unroll
  for (int r = 0; r < RS; ++r) {
    const f32x4* p = (const f32x4*)&pred[(((size_t)(r * B_ + b)) * HW + t) * 16];
    S.v[0] += p[0]; S.v[1] += p[1]; S.v[2] += p[2];
  }
  float T = 0.f;
#pragma unroll
  for (int d = 0; d < DCLS; ++d) T += S.f[d];
  const float inv = 1.f / T;
  const int lb = tl[idx];
  float se = 0.f, zt = 0.f;
#pragma unroll
  for (int d = 0; d < DCLS; ++d) {
    const float z = S.f[d] * inv;      // pred prob in [0,1]
    se += __expf(z);
    if (d == lb) zt = z;
  }
  const float logpt = zt - __logf(se);
  const float pt = __expf(zt) / se;
  const float focal = sqrtf(fmaxf(1.f - pt, 0.f));   // gamma = 0.5

  float lp = logpt, fo = focal;
#pragma unroll
  for (int off = 32; off; off >>= 1) {
    lp += __shfl_down(lp, off);
    fo += __shfl_down(fo, off);
  }
  __shared__ float rb_[8];
  const int lane = threadIdx.x & 63, wv = threadIdx.x >> 6;
  if (lane == 0) { rb_[wv] = lp; rb_[4 + wv] = fo; }
  __syncthreads();
  if (threadIdx.x == 0) {
    red[blockIdx.x * 2 + 0] = rb_[0] + rb_[1] + rb_[2] + rb_[3];
    red[blockIdx.x * 2 + 1] = rb_[4] + rb_[5] + rb_[6] + rb_[7];
  }
}

// ---------------- kernel 4: final scalar ----------------
__global__ void k_fin(const float* __restrict__ red, float* __restrict__ out) {
  const int tid = threadIdx.x;   // 64
  float lp = 0.f, fo = 0.f;
  if (tid < 32) { lp = red[tid * 2]; fo = red[tid * 2 + 1]; }
#pragma unroll
  for (int off = 16; off; off >>= 1) {
    lp += __shfl_down(lp, off);
    fo += __shfl_down(fo, off);
  }
  if (tid == 0) {
    const float ce = -lp / (float)NPIX;       // ce = -mean(log_pt)
    out[0] = ce * (fo / (float)NPIX);         // loss = ce * mean(focal)
  }
}

extern "C" void kernel_launch(void* const* d_in, const int* in_sizes, int n_in,
                              void* d_out, int out_size, void* d_ws, size_t ws_size,
                              hipStream_t stream)
{
  const float* ref  = (const float*)d_in[0];
  const float* tgt  = (const float*)d_in[1];
  const float* rl   = (const float*)d_in[2];
  const int*   tlab = (const int*)d_in[3];
  float* out = (float*)d_out;

  char* ws = (char*)d_ws;
  char* refb = ws;                                    // 32768 rows * 512 B = 16 MB (ref + tgt)
  char* tgtb = ws + (size_t)24576 * 512;              // tgt rows start at 24576
  unsigned char* lab8 = (unsigned char*)(ws + 16777216);          // 24 KB (pad 32 KB)
  float* pred = (float*)(ws + 16777216 + 32768);                  // 4 MB (RS*B*HW*16 f32)
  float* red  = (float*)(ws + 16777216 + 32768 + 4194304);        // 256 B

  k_pre<<<352, 256, 0, stream>>>(ref, tgt, rl, refb, lab8);
  k_main<<<512, 256, 0, stream>>>(refb, tgtb, lab8, pred);
  k_epi<<<32, 256, 0, stream>>>(pred, tlab, red);
  k_fin<<<1, 64, 0, stream>>>(red, out);
}